// Round 1
// baseline (152.022 us; speedup 1.0000x reference)
//
#include <hip/hip_runtime.h>
#include <math.h>

namespace {

constexpr int kW = 64;

// One block per output position (roi n, pool-row py, pool-col px).
// 256 threads x float4 = 1024 channels. All sample geometry is uniform
// per block (scalar unit); channel loads/stores are fully coalesced.
__global__ __launch_bounds__(256) void roi_pool_kernel(
    const float* __restrict__ img,    // [50, 64, 1024] f32
    const float* __restrict__ rois,   // [N, 4] f32 (y1, x1, y2, x2) in image px
    const int* __restrict__ stride_p, // scalar 16
    float* __restrict__ out) {        // [N, 7, 7, 1024] flat
  const int pos = blockIdx.x;         // n*49 + py*7 + px
  const int n   = pos / 49;
  const int r   = pos - n * 49;
  const int py  = r / 7;
  const int px  = r - py * 7;

  const float s  = (float)(*stride_p);
  // boxes = (rois / stride) / [H, W, H, W]  -- mirror np's two divisions
  const float by1 = rois[n * 4 + 0] / s / 50.0f;
  const float bx1 = rois[n * 4 + 1] / s / 64.0f;
  const float by2 = rois[n * 4 + 2] / s / 50.0f;
  const float bx2 = rois[n * 4 + 3] / s / 64.0f;

  // step = (b2 - b1) * (dim-1) / (cs-1), cs = 14
  const float stepy = (by2 - by1) * 49.0f / 13.0f;
  const float stepx = (bx2 - bx1) * 63.0f / 13.0f;

  int y0i[2], y1i[2], x0i[2], x1i[2];
  float wy[2], wx[2];
  bool vy[2], vx[2];
#pragma unroll
  for (int t = 0; t < 2; ++t) {
    const float ys = by1 * 49.0f + (float)(2 * py + t) * stepy;
    vy[t] = (ys >= 0.0f) && (ys <= 49.0f);
    const float y0f = floorf(ys);
    wy[t] = ys - y0f;
    const int y0 = min(max((int)y0f, 0), 49);
    y0i[t] = y0;
    y1i[t] = min(y0 + 1, 49);

    const float xs = bx1 * 63.0f + (float)(2 * px + t) * stepx;
    vx[t] = (xs >= 0.0f) && (xs <= 63.0f);
    const float x0f = floorf(xs);
    wx[t] = xs - x0f;
    const int x0 = min(max((int)x0f, 0), 63);
    x0i[t] = x0;
    x1i[t] = min(x0 + 1, 63);
  }

  const float4* __restrict__ img4 = (const float4*)img;
  const int c4 = threadIdx.x;  // 0..255 -> channels 4*c4..4*c4+3

  float4 m = make_float4(-INFINITY, -INFINITY, -INFINITY, -INFINITY);
#pragma unroll
  for (int ty = 0; ty < 2; ++ty) {
#pragma unroll
    for (int tx = 0; tx < 2; ++tx) {
      const float4 a = img4[(y0i[ty] * kW + x0i[tx]) * 256 + c4];
      const float4 b = img4[(y0i[ty] * kW + x1i[tx]) * 256 + c4];
      const float4 c = img4[(y1i[ty] * kW + x0i[tx]) * 256 + c4];
      const float4 d = img4[(y1i[ty] * kW + x1i[tx]) * 256 + c4];
      const float fx = wx[tx], fy = wy[ty];
      const float gx = 1.0f - fx, gy = 1.0f - fy;
      float4 v;
      v.x = (a.x * gx + b.x * fx) * gy + (c.x * gx + d.x * fx) * fy;
      v.y = (a.y * gx + b.y * fx) * gy + (c.y * gx + d.y * fx) * fy;
      v.z = (a.z * gx + b.z * fx) * gy + (c.z * gx + d.z * fx) * fy;
      v.w = (a.w * gx + b.w * fx) * gy + (c.w * gx + d.w * fx) * fy;
      if (!(vy[ty] && vx[tx])) v = make_float4(0.f, 0.f, 0.f, 0.f);
      m.x = fmaxf(m.x, v.x);
      m.y = fmaxf(m.y, v.y);
      m.z = fmaxf(m.z, v.z);
      m.w = fmaxf(m.w, v.w);
    }
  }
  ((float4*)out)[pos * 256 + c4] = m;
}

}  // namespace

extern "C" void kernel_launch(void* const* d_in, const int* in_sizes, int n_in,
                              void* d_out, int out_size, void* d_ws, size_t ws_size,
                              hipStream_t stream) {
  const float* img      = (const float*)d_in[0];
  const float* rois     = (const float*)d_in[1];
  const int*   stride_p = (const int*)d_in[2];
  float*       out      = (float*)d_out;

  const int N    = in_sizes[1] / 4;  // 1000
  const int npos = N * 49;           // 49000 blocks, one per output position
  roi_pool_kernel<<<npos, 256, 0, stream>>>(img, rois, stride_p, out);
}

// Round 3
// 110.503 us; speedup vs baseline: 1.3757x; 1.3757x over previous
//
#include <hip/hip_runtime.h>
#include <math.h>

namespace {

constexpr int kRowF4 = 64 * 256;  // float4 elements per image row (W=64, C=1024)

typedef float vf4 __attribute__((ext_vector_type(4)));

__device__ __forceinline__ int rfl(int x) { return __builtin_amdgcn_readfirstlane(x); }
__device__ __forceinline__ float rflf(float x) {
  union { float f; int i; } u;
  u.f = x;
  u.i = __builtin_amdgcn_readfirstlane(u.i);
  return u.f;
}

__device__ __forceinline__ void blend2(const float4& q0, const float4& q1,
                                       float ga, float fa, float4& b) {
  b.x = q0.x * ga + q1.x * fa;
  b.y = q0.y * ga + q1.y * fa;
  b.z = q0.z * ga + q1.z * fa;
  b.w = q0.w * ga + q1.w * fa;
}

__device__ __forceinline__ void fmax4(float4& m, const float4& v) {
  m.x = fmaxf(m.x, v.x);
  m.y = fmaxf(m.y, v.y);
  m.z = fmaxf(m.z, v.z);
  m.w = fmaxf(m.w, v.w);
}

// One block per (roi n, pool-row py): computes 7 px x 1024 channels.
// All sample geometry is block-uniform -> scalarized via readfirstlane;
// gathers are SGPR-base + shared voffset, weights are SGPR FMA operands.
// Duplicate corner rows/cols are deduped with uniform branches so the
// redundant loads are never issued.
__global__ __launch_bounds__(256) void roi_pool_kernel(
    const float* __restrict__ img,    // [50, 64, 1024] f32
    const float* __restrict__ rois,   // [N, 4] f32
    const int* __restrict__ stride_p, // scalar 16
    float* __restrict__ out) {        // [N, 7, 7, 1024]
  const int bid = blockIdx.x;
  // XCD-chunked swizzle (bijective when gridDim % 8 == 0): same-roi blocks
  // land on the same XCD's L2.
  const int chunk = gridDim.x >> 3;
  const int swz = ((gridDim.x & 7) == 0) ? ((bid & 7) * chunk + (bid >> 3)) : bid;
  const int n  = swz / 7;
  const int py = swz - n * 7;
  const int c4 = threadIdx.x;  // float4 channel index 0..255

  const float s = (float)(*stride_p);
  // boxes = (rois / stride) / [H, W, H, W] -- mirror reference op order
  const float by1 = rois[n * 4 + 0] / s / 50.0f;
  const float bx1 = rois[n * 4 + 1] / s / 64.0f;
  const float by2 = rois[n * 4 + 2] / s / 50.0f;
  const float bx2 = rois[n * 4 + 3] / s / 64.0f;
  const float stepy = (by2 - by1) * 49.0f / 13.0f;
  const float stepx = (bx2 - bx1) * 63.0f / 13.0f;

  // ---- row geometry for the two sample-rows of this pooled row ----
  const float ys0 = by1 * 49.0f + (float)(2 * py + 0) * stepy;
  const float ys1 = by1 * 49.0f + (float)(2 * py + 1) * stepy;
  const float vy0 = (ys0 >= 0.0f && ys0 <= 49.0f) ? 1.0f : 0.0f;
  const float vy1 = (ys1 >= 0.0f && ys1 <= 49.0f) ? 1.0f : 0.0f;
  const float yf0 = floorf(ys0), yf1 = floorf(ys1);
  const float wy0 = ys0 - yf0, wy1 = ys1 - yf1;
  const int r0i = min(max((int)yf0, 0), 49);
  const int r2i = min(max((int)yf1, 0), 49);
  const int r0 = rfl(r0i);
  const int r1 = rfl(min(r0i + 1, 49));
  const int r2 = rfl(r2i);
  const int r3 = rfl(min(r2i + 1, 49));
  // validity folded into the y-weights (invalid sample -> exact 0, then max)
  const float gy0 = rflf((1.0f - wy0) * vy0);
  const float fy0 = rflf(wy0 * vy0);
  const float gy1 = rflf((1.0f - wy1) * vy1);
  const float fy1 = rflf(wy1 * vy1);

  const float4* __restrict__ img4 = (const float4*)img;
  float4* __restrict__ out4 =
      (float4*)out + (size_t)(n * 49 + py * 7) * 256 + c4;

  const float xb = bx1 * 63.0f;

#pragma unroll 1
  for (int px = 0; px < 7; ++px) {
    const float xs0 = xb + (float)(2 * px + 0) * stepx;
    const float xs1 = xb + (float)(2 * px + 1) * stepx;
    const float vx0 = (xs0 >= 0.0f && xs0 <= 63.0f) ? 1.0f : 0.0f;
    const float vx1 = (xs1 >= 0.0f && xs1 <= 63.0f) ? 1.0f : 0.0f;
    const float xf0 = floorf(xs0), xf1 = floorf(xs1);
    const float wx0 = xs0 - xf0, wx1 = xs1 - xf1;
    const int c0i = min(max((int)xf0, 0), 63);
    const int c2i = min(max((int)xf1, 0), 63);
    const int c0 = rfl(c0i);
    const int c1 = rfl(min(c0i + 1, 63));
    const int c2 = rfl(c2i);
    const int c3 = rfl(min(c2i + 1, 63));
    const float gx0 = rflf((1.0f - wx0) * vx0);
    const float fx0 = rflf(wx0 * vx0);
    const float gx1 = rflf((1.0f - wx1) * vx1);
    const float fx1 = rflf(wx1 * vx1);

    // uniform dedup conditions (c0<=c1, c0<=c2<=c3; same ordering for rows)
    const bool c2e0 = (c2 == c0), c2e1 = (c2 == c1);
    const bool c3e1 = (c3 == c1), c3e2 = (c3 == c2);
    const int co0 = c0 * 256, co1 = c1 * 256, co2 = c2 * 256, co3 = c3 * 256;

    // Load row r's needed corners (deduped) and x-blend into the two
    // per-sample values. Row registers die immediately after the blend.
    auto rowblend = [&](int r, float4& b0, float4& b1) {
      const float4* rp = img4 + r * kRowF4;  // SGPR base
      const float4 q0 = rp[co0 + c4];
      const float4 q1 = rp[co1 + c4];
      float4 q2, q3;
      if (c2e0)      q2 = q0;
      else if (c2e1) q2 = q1;
      else           q2 = rp[co2 + c4];
      if (c3e1)      q3 = q1;
      else if (c3e2) q3 = q2;
      else           q3 = rp[co3 + c4];
      blend2(q0, q1, gx0, fx0, b0);
      blend2(q2, q3, gx1, fx1, b1);
    };

    float4 b00, b01, b10, b11, b20, b21, b30, b31;
    rowblend(r0, b00, b01);
    if (r1 == r0) { b10 = b00; b11 = b01; }
    else rowblend(r1, b10, b11);
    if (r2 == r0)      { b20 = b00; b21 = b01; }
    else if (r2 == r1) { b20 = b10; b21 = b11; }
    else rowblend(r2, b20, b21);
    if (r3 == r1)      { b30 = b10; b31 = b11; }
    else if (r3 == r2) { b30 = b20; b31 = b21; }
    else rowblend(r3, b30, b31);

    // y-blend the 4 samples of the 2x2 max-pool window and reduce
    float4 m, v;
    blend2(b00, b10, gy0, fy0, m);
    blend2(b01, b11, gy0, fy0, v);
    fmax4(m, v);
    blend2(b20, b30, gy1, fy1, v);
    fmax4(m, v);
    blend2(b21, b31, gy1, fy1, v);
    fmax4(m, v);

    // nontemporal: don't let the 196 MB output stream evict the image from L2.
    // (native ext-vector type required by the builtin; float4 class won't do)
    vf4 mv;
    mv.x = m.x; mv.y = m.y; mv.z = m.z; mv.w = m.w;
    __builtin_nontemporal_store(mv, (vf4*)(out4 + px * 256));
  }
}

}  // namespace

extern "C" void kernel_launch(void* const* d_in, const int* in_sizes, int n_in,
                              void* d_out, int out_size, void* d_ws, size_t ws_size,
                              hipStream_t stream) {
  const float* img      = (const float*)d_in[0];
  const float* rois     = (const float*)d_in[1];
  const int*   stride_p = (const int*)d_in[2];
  float*       out      = (float*)d_out;

  const int N = in_sizes[1] / 4;      // 1000
  const int nblocks = N * 7;          // one block per (roi, pool-row)
  roi_pool_kernel<<<nblocks, 256, 0, stream>>>(img, rois, stride_p, out);
}

// Round 4
// 109.709 us; speedup vs baseline: 1.3857x; 1.0072x over previous
//
#include <hip/hip_runtime.h>
#include <math.h>

namespace {

constexpr int kRowF4 = 64 * 256;  // float4 elements per image row (W=64, C=1024)

typedef float vf4 __attribute__((ext_vector_type(4)));

__device__ __forceinline__ int rfl(int x) { return __builtin_amdgcn_readfirstlane(x); }
__device__ __forceinline__ float rflf(float x) {
  union { float f; int i; } u;
  u.f = x;
  u.i = __builtin_amdgcn_readfirstlane(u.i);
  return u.f;
}

__device__ __forceinline__ vf4 splat4(float x) {
  vf4 v = {x, x, x, x};
  return v;
}

// One block per (roi n, pool-row py): computes 7 px x 1024 channels.
// Geometry is block-uniform -> scalarized via readfirstlane; gathers are
// SGPR-base + shared voffset; duplicate corner rows/cols deduped with
// uniform branches. px loop fully unrolled for VMEM ILP; blends are native
// <4 x float> vector ops so the backend can use packed-FP32 VOP3P.
__global__ __launch_bounds__(256) void roi_pool_kernel(
    const float* __restrict__ img,    // [50, 64, 1024] f32
    const float* __restrict__ rois,   // [N, 4] f32
    const int* __restrict__ stride_p, // scalar 16
    float* __restrict__ out) {        // [N, 7, 7, 1024]
  const int bid = blockIdx.x;
  // XCD-chunked swizzle (bijective when gridDim % 8 == 0)
  const int chunk = gridDim.x >> 3;
  const int swz = ((gridDim.x & 7) == 0) ? ((bid & 7) * chunk + (bid >> 3)) : bid;
  const int n  = swz / 7;
  const int py = swz - n * 7;
  const int c4 = threadIdx.x;  // float4 channel index 0..255

  const float s = (float)(*stride_p);
  // boxes = (rois / stride) / [H, W, H, W] -- mirror reference op order
  const float by1 = rois[n * 4 + 0] / s / 50.0f;
  const float bx1 = rois[n * 4 + 1] / s / 64.0f;
  const float by2 = rois[n * 4 + 2] / s / 50.0f;
  const float bx2 = rois[n * 4 + 3] / s / 64.0f;
  const float stepy = (by2 - by1) * 49.0f / 13.0f;
  const float stepx = (bx2 - bx1) * 63.0f / 13.0f;

  // ---- row geometry for the two sample-rows of this pooled row ----
  const float ys0 = by1 * 49.0f + (float)(2 * py + 0) * stepy;
  const float ys1 = by1 * 49.0f + (float)(2 * py + 1) * stepy;
  const float vy0 = (ys0 >= 0.0f && ys0 <= 49.0f) ? 1.0f : 0.0f;
  const float vy1 = (ys1 >= 0.0f && ys1 <= 49.0f) ? 1.0f : 0.0f;
  const float yf0 = floorf(ys0), yf1 = floorf(ys1);
  const float wy0 = ys0 - yf0, wy1 = ys1 - yf1;
  const int r0i = min(max((int)yf0, 0), 49);
  const int r2i = min(max((int)yf1, 0), 49);
  const int r0 = rfl(r0i);
  const int r1 = rfl(min(r0i + 1, 49));
  const int r2 = rfl(r2i);
  const int r3 = rfl(min(r2i + 1, 49));
  // validity folded into the y-weights (invalid sample -> exact 0, then max)
  const vf4 gy0 = splat4(rflf((1.0f - wy0) * vy0));
  const vf4 fy0 = splat4(rflf(wy0 * vy0));
  const vf4 gy1 = splat4(rflf((1.0f - wy1) * vy1));
  const vf4 fy1 = splat4(rflf(wy1 * vy1));

  const vf4* __restrict__ img4 = (const vf4*)img;
  vf4* __restrict__ out4 = (vf4*)out + (size_t)(n * 49 + py * 7) * 256 + c4;

  const float xb = bx1 * 63.0f;

#pragma unroll
  for (int px = 0; px < 7; ++px) {
    const float xs0 = xb + (float)(2 * px + 0) * stepx;
    const float xs1 = xb + (float)(2 * px + 1) * stepx;
    const float vx0 = (xs0 >= 0.0f && xs0 <= 63.0f) ? 1.0f : 0.0f;
    const float vx1 = (xs1 >= 0.0f && xs1 <= 63.0f) ? 1.0f : 0.0f;
    const float xf0 = floorf(xs0), xf1 = floorf(xs1);
    const float wx0 = xs0 - xf0, wx1 = xs1 - xf1;
    const int c0i = min(max((int)xf0, 0), 63);
    const int c2i = min(max((int)xf1, 0), 63);
    const int c0 = rfl(c0i);
    const int c1 = rfl(min(c0i + 1, 63));
    const int c2 = rfl(c2i);
    const int c3 = rfl(min(c2i + 1, 63));
    const vf4 gx0 = splat4(rflf((1.0f - wx0) * vx0));
    const vf4 fx0 = splat4(rflf(wx0 * vx0));
    const vf4 gx1 = splat4(rflf((1.0f - wx1) * vx1));
    const vf4 fx1 = splat4(rflf(wx1 * vx1));

    // uniform dedup conditions
    const bool c2e0 = (c2 == c0), c2e1 = (c2 == c1);
    const bool c3e1 = (c3 == c1), c3e2 = (c3 == c2);
    const int co0 = c0 * 256, co1 = c1 * 256, co2 = c2 * 256, co3 = c3 * 256;

    // Load row r's needed corners (deduped) and x-blend into the two
    // per-sample values.
    auto rowblend = [&](int r, vf4& b0, vf4& b1) {
      const vf4* rp = img4 + r * kRowF4;  // uniform base
      const vf4 q0 = rp[co0 + c4];
      const vf4 q1 = rp[co1 + c4];
      vf4 q2, q3;
      if (c2e0)      q2 = q0;
      else if (c2e1) q2 = q1;
      else           q2 = rp[co2 + c4];
      if (c3e1)      q3 = q1;
      else if (c3e2) q3 = q2;
      else           q3 = rp[co3 + c4];
      b0 = q0 * gx0 + q1 * fx0;
      b1 = q2 * gx1 + q3 * fx1;
    };

    vf4 b00, b01, b10, b11, b20, b21, b30, b31;
    rowblend(r0, b00, b01);
    if (r1 == r0) { b10 = b00; b11 = b01; }
    else rowblend(r1, b10, b11);
    if (r2 == r0)      { b20 = b00; b21 = b01; }
    else if (r2 == r1) { b20 = b10; b21 = b11; }
    else rowblend(r2, b20, b21);
    if (r3 == r1)      { b30 = b10; b31 = b11; }
    else if (r3 == r2) { b30 = b20; b31 = b21; }
    else rowblend(r3, b30, b31);

    // y-blend the 4 samples of the 2x2 max-pool window and reduce
    vf4 m = b00 * gy0 + b10 * fy0;
    vf4 v = b01 * gy0 + b11 * fy0;
    m = __builtin_elementwise_max(m, v);
    v = b20 * gy1 + b30 * fy1;
    m = __builtin_elementwise_max(m, v);
    v = b21 * gy1 + b31 * fy1;
    m = __builtin_elementwise_max(m, v);

    // nontemporal: don't let the 196 MB output stream evict the image from L2
    __builtin_nontemporal_store(m, out4 + px * 256);
  }
}

}  // namespace

extern "C" void kernel_launch(void* const* d_in, const int* in_sizes, int n_in,
                              void* d_out, int out_size, void* d_ws, size_t ws_size,
                              hipStream_t stream) {
  const float* img      = (const float*)d_in[0];
  const float* rois     = (const float*)d_in[1];
  const int*   stride_p = (const int*)d_in[2];
  float*       out      = (float*)d_out;

  const int N = in_sizes[1] / 4;      // 1000
  const int nblocks = N * 7;          // one block per (roi, pool-row)
  roi_pool_kernel<<<nblocks, 256, 0, stream>>>(img, rois, stride_p, out);
}